// Round 7
// baseline (488.215 us; speedup 1.0000x reference)
//
#include <hip/hip_runtime.h>
#include <math.h>

namespace {

typedef short short8 __attribute__((ext_vector_type(8)));
typedef int i32x4 __attribute__((ext_vector_type(4)));
typedef float f32x4 __attribute__((ext_vector_type(4)));

constexpr int kB = 4, kT = 2048, kD = 512, kE = 4, kC = 1024, kHE = 512,
              kO = 512, kEC = 4096;

__device__ __forceinline__ unsigned short f2bf(float f) {
    unsigned int u = __float_as_uint(f);
    u += 0x7fffu + ((u >> 16) & 1u);   // RNE
    return (unsigned short)(u >> 16);
}

__device__ __forceinline__ float gelu_exact(float v) {
    return 0.5f * v * (1.0f + erff(v * 0.70710678118654752f));
}

#define GLDS16(g, l)                                                      \
    __builtin_amdgcn_global_load_lds(                                     \
        (const __attribute__((address_space(1))) unsigned int*)(g),       \
        (__attribute__((address_space(3))) unsigned int*)(l), 16, 0, 0)

// ---------------------------------------------------------------------------
// Transpose+cast (v2, split launches — fused variant measured 118 µs @31% HBM
// in R4/R6, split is faster): in[z] R x Cc fp32 -> out[z] Cc x R bf16.
// 64(r) x 32(c) tiles; both global phases 128 B per 32-lane group.
__global__ __launch_bounds__(256)
void transpose_cast(const float* __restrict__ in, unsigned short* __restrict__ out,
                    int R, int Cc, long long sIn, long long sOut)
{
    __shared__ float tile[64][33];
    const int z = blockIdx.z;
    const float* ip = in + (long long)z * sIn;
    unsigned short* op = out + (long long)z * sOut;
    const int c0 = blockIdx.x * 32, r0 = blockIdx.y * 64;
    const int tx = threadIdx.x & 31, ty = threadIdx.x >> 5;  // ty 0..7
#pragma unroll
    for (int i = 0; i < 8; ++i) {
        const int r = ty + i * 8;
        tile[r][tx] = ip[(size_t)(r0 + r) * Cc + c0 + tx];
    }
    __syncthreads();
#pragma unroll
    for (int i = 0; i < 4; ++i) {
        const int c = ty + i * 8;
        const unsigned lo = f2bf(tile[tx * 2][c]);
        const unsigned hi = f2bf(tile[tx * 2 + 1][c]);
        *(unsigned*)&op[(size_t)(c0 + c) * R + r0 + tx * 2] = lo | (hi << 16);
    }
}

// ---------------------------------------------------------------------------
// MFMA GEMM: C[z] = A[z%zModA] (MxK) * B[z%zModB]^T (NxK, k-contig bf16).
// B element (n,k) at ((k>>bShift)*N + n)<<bShift | (k & mask).
// MODE: 0 = bf16 store, 1 = bf16 store of gelu(acc+bias[n]), 3 = f32 acc+bias[n].
// ASRC: 0 = A bf16 k-contig via global_load_lds (R3-verbatim path)
//       1 = A fp32 K-MAJOR  (elem = k*M + m)  — mask consumed directly
//       2 = A fp32 M-major  (elem = m*K + k)  — comb consumed directly
// fp32-A is reg-staged: issue loads for tile T+2 early, cvt_pk to bf16 +
// swizzled ds_write after this iter's MFMAs (write slot = (k>>3)^(row&7),
// identical to the GLDS-B swizzle convention, so READ16 is unchanged).
// vmcnt ledger per iter: issue A(T+2)[NA] + B(T+2)[4]; vmcnt(NA+4) forces
// B(T+1) (oldest) before the barrier; vmcnt(4) after MFMA -> A(T+2) regs
// arrived (only B(T+2) outstanding).
template <int MODE, int ASRC>
__global__ __launch_bounds__(256, 1)
void mfma_gemm(const void* __restrict__ AallV,
               const unsigned short* __restrict__ Ball,
               const float* __restrict__ biasAll,
               void* __restrict__ Call,
               int M, int N, int K,
               long long sA, long long sB, long long sC,
               int zModA, int zModB, int zModBias, int biasStride, int bShift)
{
    __shared__ unsigned short As[4][128 * 64];
    __shared__ unsigned short Bs[4][128 * 64];

    const int z = blockIdx.z;
    const unsigned short* Ab =
        (ASRC == 0) ? (const unsigned short*)AallV + (long long)(z % zModA) * sA
                    : nullptr;
    const float* Af =
        (ASRC != 0) ? (const float*)AallV + (long long)(z % zModA) * sA
                    : nullptr;
    const unsigned short* Bb = Ball + (long long)(z % zModB) * sB;
    const float* bias =
        (MODE != 0) ? biasAll + (long long)(z % zModBias) * biasStride : nullptr;

    // T1: XCD-aware remap (bijective when nwg%8==0).
    const int gx = gridDim.x;
    int lin = blockIdx.y * gx + blockIdx.x;
    const int nwg = gx * gridDim.y;
    if ((nwg & 7) == 0) {
        const int q = nwg >> 3;
        lin = (lin & 7) * q + (lin >> 3);
    }
    const int gxs = 31 - __clz(gx);
    const int bx = lin & (gx - 1);
    const int by = lin >> gxs;
    const int row0 = by * 128;
    const int colB = bx * 128;

    const int t = threadIdx.x;
    const int lane = t & 63;
    const int w = t >> 6;
    const int wrow = w * 32;
    const int l8r = lane >> 3;
    const int l8c = ((lane & 7) ^ l8r) * 8;   // pre-swizzled k-slot for GLDS

    const int wm = (w >> 1) * 64;
    const int wn = (w & 1) * 64;
    const int fr = lane & 15;
    const int fq = (lane >> 4) * 8;
    const int fsw = (fr & 7) * 8;

    const unsigned int bMask = (1u << bShift) - 1u;

    f32x4 acc[4][4] = {};

    // fp32-A staging lane mapping + precomputed swizzled LDS element offset.
    float ar[8][4];                             // in-flight A regs (32 VGPR)
    const int a1_m = t & 15;                    // ASRC1: row = p*16 + a1_m
    const int a1_k = (t >> 4) * 4;              //        k-local
    const int a2_m = t >> 4;                    // ASRC2: row = p*16 + a2_m
    const int a2_k = (t & 15) * 4;              //        k-local
    const int aw_eoff =
        (ASRC == 1)
            ? (a1_m * 64 + (((a1_k >> 3) ^ (a1_m & 7)) << 3) + (a1_k & 7))
            : (a2_m * 64 + (((a2_k >> 3) ^ (a2_m & 7)) << 3) + (a2_k & 7));

    const unsigned aB0 =
        (unsigned)(size_t)(const __attribute__((address_space(3))) unsigned short*)
            &As[0][0] +
        (unsigned)(((wm + fr) * 64 + (fq ^ fsw)) * 2);
    const unsigned bB0 =
        (unsigned)(size_t)(const __attribute__((address_space(3))) unsigned short*)
            &Bs[0][0] +
        (unsigned)(((wn + fr) * 64 + (fq ^ fsw)) * 2);

    struct FragSet { i32x4 a0[4], a1[4], b0[4], b1[4]; };
    FragSet R0, R1;

#define DSR0(d, a) asm volatile("ds_read_b128 %0, %1" : "=v"(d) : "v"(a))
#define DSR1(d, a) asm volatile("ds_read_b128 %0, %1 offset:2048" : "=v"(d) : "v"(a))
#define DSR2(d, a) asm volatile("ds_read_b128 %0, %1 offset:4096" : "=v"(d) : "v"(a))
#define DSR3(d, a) asm volatile("ds_read_b128 %0, %1 offset:6144" : "=v"(d) : "v"(a))

#define READ16(R, CB)                                                         \
    do {                                                                      \
        const unsigned A0c = aB0 + (CB) * 16384u, A1c = A0c ^ 64u;            \
        const unsigned B0c = bB0 + (CB) * 16384u, B1c = B0c ^ 64u;            \
        DSR0(R.a0[0], A0c); DSR1(R.a0[1], A0c); DSR2(R.a0[2], A0c); DSR3(R.a0[3], A0c); \
        DSR0(R.b0[0], B0c); DSR1(R.b0[1], B0c); DSR2(R.b0[2], B0c); DSR3(R.b0[3], B0c); \
        DSR0(R.a1[0], A1c); DSR1(R.a1[1], A1c); DSR2(R.a1[2], A1c); DSR3(R.a1[3], A1c); \
        DSR0(R.b1[0], B1c); DSR1(R.b1[1], B1c); DSR2(R.b1[2], B1c); DSR3(R.b1[3], B1c); \
    } while (0)

#define MFMA16(R)                                                             \
    do {                                                                      \
        _Pragma("unroll") for (int i_ = 0; i_ < 4; ++i_)                      \
            _Pragma("unroll") for (int j_ = 0; j_ < 4; ++j_)                  \
                acc[i_][j_] = __builtin_amdgcn_mfma_f32_16x16x32_bf16(        \
                    __builtin_bit_cast(short8, R.a0[i_]),                     \
                    __builtin_bit_cast(short8, R.b0[j_]), acc[i_][j_], 0, 0, 0); \
        _Pragma("unroll") for (int i_ = 0; i_ < 4; ++i_)                      \
            _Pragma("unroll") for (int j_ = 0; j_ < 4; ++j_)                  \
                acc[i_][j_] = __builtin_amdgcn_mfma_f32_16x16x32_bf16(        \
                    __builtin_bit_cast(short8, R.a1[i_]),                     \
                    __builtin_bit_cast(short8, R.b1[j_]), acc[i_][j_], 0, 0, 0); \
    } while (0)

#define STAGE_B(buf, k0)                                                      \
    do {                                                                      \
        _Pragma("unroll")                                                     \
        for (int r = 0; r < 4; ++r) {                                         \
            const int bn = colB + wrow + r * 8 + l8r;                         \
            const int gk = (k0) + l8c;                                        \
            const size_t boff =                                               \
                (((size_t)(gk >> bShift) * N + bn) << bShift) + (gk & bMask); \
            GLDS16(Bb + boff, &Bs[buf][(wrow + r * 8) * 64]);                 \
        }                                                                     \
    } while (0)

#define STAGE_A_GLDS(buf, k0)                                                 \
    do {                                                                      \
        _Pragma("unroll")                                                     \
        for (int r = 0; r < 4; ++r) {                                         \
            const int arow = row0 + wrow + r * 8 + l8r;                       \
            GLDS16(Ab + (size_t)arow * K + ((k0) + l8c),                      \
                   &As[buf][(wrow + r * 8) * 64]);                            \
        }                                                                     \
    } while (0)

#define A_ISSUE(k0)                                                           \
    do {                                                                      \
        if constexpr (ASRC == 1) {                                            \
            _Pragma("unroll")                                                 \
            for (int p_ = 0; p_ < 8; ++p_) {                                  \
                const size_t b_ =                                             \
                    (size_t)((k0) + a1_k) * M + row0 + p_ * 16 + a1_m;        \
                ar[p_][0] = Af[b_];                                           \
                ar[p_][1] = Af[b_ + (size_t)M];                               \
                ar[p_][2] = Af[b_ + 2 * (size_t)M];                           \
                ar[p_][3] = Af[b_ + 3 * (size_t)M];                           \
            }                                                                 \
        } else {                                                              \
            _Pragma("unroll")                                                 \
            for (int p_ = 0; p_ < 8; ++p_) {                                  \
                const float4 v_ = *(const float4*)&Af[                        \
                    (size_t)(row0 + p_ * 16 + a2_m) * K + (k0) + a2_k];       \
                ar[p_][0] = v_.x; ar[p_][1] = v_.y;                           \
                ar[p_][2] = v_.z; ar[p_][3] = v_.w;                           \
            }                                                                 \
        }                                                                     \
    } while (0)

#define A_WRITE(buf)                                                          \
    do {                                                                      \
        _Pragma("unroll")                                                     \
        for (int p_ = 0; p_ < 8; ++p_) {                                      \
            unsigned lo_, hi_;                                                \
            asm("v_cvt_pk_bf16_f32 %0, %1, %2"                                \
                : "=v"(lo_) : "v"(ar[p_][0]), "v"(ar[p_][1]));                \
            asm("v_cvt_pk_bf16_f32 %0, %1, %2"                                \
                : "=v"(hi_) : "v"(ar[p_][2]), "v"(ar[p_][3]));                \
            *(uint2*)&As[buf][aw_eoff + p_ * 1024] = make_uint2(lo_, hi_);    \
        }                                                                     \
    } while (0)

#define ITER_BF16(T, CBRD, CBST, Rmf, Rrd)                                    \
    do {                                                                      \
        STAGE_A_GLDS(CBST, ((T) + 2) * 64);                                   \
        STAGE_B(CBST, ((T) + 2) * 64);                                        \
        asm volatile("s_waitcnt vmcnt(8)" ::: "memory");                      \
        __builtin_amdgcn_s_barrier();                                         \
        READ16(Rrd, CBRD);                                                    \
        MFMA16(Rmf);                                                          \
        asm volatile("s_waitcnt lgkmcnt(0)" ::: "memory");                    \
        __builtin_amdgcn_sched_barrier(0);                                    \
    } while (0)

#define ITER_F32(T, CBRD, CBST, Rmf, Rrd)                                     \
    do {                                                                      \
        A_ISSUE(((T) + 2) * 64);                                              \
        STAGE_B(CBST, ((T) + 2) * 64);                                        \
        if constexpr (ASRC == 1)                                              \
            asm volatile("s_waitcnt vmcnt(36)" ::: "memory");                 \
        else                                                                  \
            asm volatile("s_waitcnt vmcnt(12)" ::: "memory");                 \
        __builtin_amdgcn_sched_barrier(0);                                    \
        __builtin_amdgcn_s_barrier();                                         \
        READ16(Rrd, CBRD);                                                    \
        MFMA16(Rmf);                                                          \
        asm volatile("s_waitcnt vmcnt(4)" ::: "memory");                      \
        __builtin_amdgcn_sched_barrier(0);                                    \
        A_WRITE(CBST);                                                        \
        asm volatile("s_waitcnt lgkmcnt(0)" ::: "memory");                    \
        __builtin_amdgcn_sched_barrier(0);                                    \
    } while (0)

    const int nt = K / 64;   // 8, 32, or 64 (always % 4 == 0, >= 8)

    if constexpr (ASRC == 0) {
        STAGE_A_GLDS(0, 0); STAGE_B(0, 0);
        STAGE_A_GLDS(1, 64); STAGE_B(1, 64);
        asm volatile("s_waitcnt vmcnt(8)" ::: "memory");
        __builtin_amdgcn_s_barrier();
        READ16(R0, 0);
        asm volatile("s_waitcnt lgkmcnt(0)" ::: "memory");
        __builtin_amdgcn_sched_barrier(0);

        for (int t0 = 0; t0 + 4 < nt; t0 += 4) {
            ITER_BF16(t0 + 0, 1, 2, R0, R1);
            ITER_BF16(t0 + 1, 2, 3, R1, R0);
            ITER_BF16(t0 + 2, 3, 0, R0, R1);
            ITER_BF16(t0 + 3, 0, 1, R1, R0);
        }
        ITER_BF16(nt - 4, 1, 2, R0, R1);
        ITER_BF16(nt - 3, 2, 3, R1, R0);
        asm volatile("s_waitcnt vmcnt(0)" ::: "memory");
        __builtin_amdgcn_s_barrier();
        READ16(R1, 3);
        MFMA16(R0);
        asm volatile("s_waitcnt lgkmcnt(0)" ::: "memory");
        __builtin_amdgcn_sched_barrier(0);
        MFMA16(R1);
    } else {
        // prologue: A(0),A(1) via regs->LDS; B(0),B(1) via GLDS.
        A_ISSUE(0);
        asm volatile("s_waitcnt vmcnt(0)" ::: "memory");
        __builtin_amdgcn_sched_barrier(0);
        A_WRITE(0);
        A_ISSUE(64);
        STAGE_B(0, 0);
        STAGE_B(1, 64);
        asm volatile("s_waitcnt vmcnt(8)" ::: "memory");  // A(1) regs arrived
        __builtin_amdgcn_sched_barrier(0);
        A_WRITE(1);
        asm volatile("s_waitcnt lgkmcnt(0)" ::: "memory");
        asm volatile("s_waitcnt vmcnt(4)" ::: "memory");  // B(0) complete
        __builtin_amdgcn_sched_barrier(0);
        __builtin_amdgcn_s_barrier();
        READ16(R0, 0);
        asm volatile("s_waitcnt lgkmcnt(0)" ::: "memory");
        __builtin_amdgcn_sched_barrier(0);

        for (int t0 = 0; t0 + 4 < nt; t0 += 4) {
            ITER_F32(t0 + 0, 1, 2, R0, R1);
            ITER_F32(t0 + 1, 2, 3, R1, R0);
            ITER_F32(t0 + 2, 3, 0, R0, R1);
            ITER_F32(t0 + 3, 0, 1, R1, R0);
        }
        ITER_F32(nt - 4, 1, 2, R0, R1);
        ITER_F32(nt - 3, 2, 3, R1, R0);
        asm volatile("s_waitcnt vmcnt(0)" ::: "memory");  // B(nt-1)
        __builtin_amdgcn_s_barrier();
        READ16(R1, 3);
        MFMA16(R0);
        asm volatile("s_waitcnt lgkmcnt(0)" ::: "memory");
        __builtin_amdgcn_sched_barrier(0);
        MFMA16(R1);
    }

#undef ITER_F32
#undef ITER_BF16
#undef A_WRITE
#undef A_ISSUE
#undef STAGE_A_GLDS
#undef STAGE_B
#undef MFMA16
#undef READ16
#undef DSR0
#undef DSR1
#undef DSR2
#undef DSR3

    // Epilogue. C/D layout: col = lane&15, row = (lane>>4)*4 + reg  [m89/m91].
    const long long cz = (long long)z * sC;
#pragma unroll
    for (int i = 0; i < 4; ++i) {
        const int rowb = row0 + wm + i * 16 + (lane >> 4) * 4;
#pragma unroll
        for (int j = 0; j < 4; ++j) {
            const int col = colB + wn + j * 16 + fr;
            const float bv = (MODE != 0) ? bias[col] : 0.0f;
#pragma unroll
            for (int r = 0; r < 4; ++r) {
                const float v = acc[i][j][r];
                const size_t idx = (size_t)cz + (size_t)(rowb + r) * N + col;
                if (MODE == 0)
                    ((unsigned short*)Call)[idx] = f2bf(v);
                else if (MODE == 1)
                    ((unsigned short*)Call)[idx] = f2bf(gelu_exact(v + bv));
                else
                    ((float*)Call)[idx] = v + bv;
            }
        }
    }
}

}  // namespace

extern "C" void kernel_launch(void* const* d_in, const int* in_sizes, int n_in,
                              void* d_out, int out_size, void* d_ws, size_t ws_size,
                              hipStream_t stream)
{
    const float* x    = (const float*)d_in[0];  // (B,T,D)
    const float* mask = (const float*)d_in[1];  // (B,T,EC) fp32 — consumed directly
    const float* comb = (const float*)d_in[2];  // (B,T,EC) fp32 — consumed directly
    const float* w1   = (const float*)d_in[3];  // (E,D,HE)
    const float* b1   = (const float*)d_in[4];  // (E,HE)
    const float* w2   = (const float*)d_in[5];  // (E,HE,O)
    const float* b2   = (const float*)d_in[6];  // (O,)
    float* out = (float*)d_out;                 // (B,T,O) fp32

    // Workspace (bf16 elements) — mask/comb regions no longer needed.
    unsigned short* ws  = (unsigned short*)d_ws;
    unsigned short* xT  = ws;                    //  4,194,304: [B][D][T]
    unsigned short* w1T = xT + 4194304;          //  1,048,576: [E][HE][D]
    unsigned short* w2T = w1T + 1048576;         //  1,048,576: [E][O][HE]
    unsigned short* xd  = w2T + 1048576;         //  8,388,608: [B][EC][D]; reused as yT
    unsigned short* h   = xd + 8388608;          //  8,388,608: [B*E][C][HE]
    unsigned short* yT  = xd;

    dim3 blk(256);

    // --- conversions: only x, w1, w2 (mask transpose & comb cast deleted) ---
    transpose_cast<<<dim3(kD / 32, kT / 64, kB), blk, 0, stream>>>(
        x, xT, kT, kD, (long long)kT * kD, (long long)kT * kD);
    transpose_cast<<<dim3(kHE / 32, kD / 64, kE), blk, 0, stream>>>(
        w1, w1T, kD, kHE, (long long)kD * kHE, (long long)kD * kHE);
    transpose_cast<<<dim3(kO / 32, kHE / 64, kE), blk, 0, stream>>>(
        w2, w2T, kHE, kO, (long long)kHE * kO, (long long)kHE * kO);

    // --- stage 1: xd[b][ec][d] = sum_t mask[b][t][ec] * xT[b][d][t] ---
    // A = mask fp32 K-major (elem = t*EC + ec = k*M + m).
    mfma_gemm<0, 1><<<dim3(kD / 128, kEC / 128, kB), blk, 0, stream>>>(
        mask, xT, nullptr, xd, kEC, kD, kT,
        (long long)kEC * kT, (long long)kD * kT, (long long)kEC * kD,
        kB, kB, 1, 0, 11);

    // --- stage 2: h[g][c][he] = gelu(xd[g]*w1T[e]^T + b1[e]) ---
    mfma_gemm<1, 0><<<dim3(kHE / 128, kC / 128, kB * kE), blk, 0, stream>>>(
        xd, w1T, b1, h, kC, kHE, kD,
        (long long)kC * kD, (long long)kHE * kD, (long long)kC * kHE,
        kB * kE, kE, kE, kHE, 9);

    // --- stage 3 (swapped): yT[g][o][c] = w2T[e]*h[g]^T ---
    mfma_gemm<0, 0><<<dim3(kC / 128, kO / 128, kB * kE), blk, 0, stream>>>(
        w2T, h, nullptr, yT, kO, kC, kHE,
        (long long)kO * kHE, (long long)kC * kHE, (long long)kO * kC,
        kE, kB * kE, 1, 0, 9);

    // --- stage 4: out[b][t][o] = sum_ec comb[b][t][ec]*yT[b][e][o][c] + b2 ---
    // A = comb fp32 M-major (elem = t*EC + ec = m*K + k, already k-contig).
    mfma_gemm<3, 2><<<dim3(kO / 128, kT / 128, kB), blk, 0, stream>>>(
        comb, yT, b2, out, kT, kO, kEC,
        (long long)kT * kEC, (long long)kE * kO * kC, (long long)kT * kO,
        kB, kB, 1, 0, 10);
}